// Round 1
// baseline (568.507 us; speedup 1.0000x reference)
//
#include <hip/hip_runtime.h>
#include <hip/hip_bf16.h>

#define HW 3136      // 56*56
#define CTOT 64
#define NTOT 128
#define BB 16
#define TTT 8

// ---------- helpers ----------
static __device__ __forceinline__ float bf2f(unsigned short u) {
    union { unsigned int ui; float f; } v;
    v.ui = ((unsigned int)u) << 16;
    return v.f;
}
static __device__ __forceinline__ unsigned short f2bf(float f) {
    union { float f; unsigned int u; } v;
    v.f = f;
    unsigned int u = v.u;
    unsigned int r = (u + 0x7fffu + ((u >> 16) & 1u)) >> 16;  // round-nearest-even
    return (unsigned short)r;
}

// ---------- K1: attn = sigmoid(relu(conv2d(x, attn_w) + attn_b)) ----------
// grid (14, 128), block (64, 4). One thread: one (n,h,w), all 4 heads.
__global__ __launch_bounds__(256) void k_attn(const float* __restrict__ x,
                                              const float* __restrict__ aw,
                                              const float* __restrict__ ab,
                                              float* __restrict__ attn) {
    const int w = threadIdx.x;                 // 0..63, active < 56
    const int h = blockIdx.x * 4 + threadIdx.y;
    const int n = blockIdx.y;
    if (w >= 56) return;

    float a0 = ab[0], a1 = ab[1], a2 = ab[2], a3 = ab[3];
    const float* xn = x + (size_t)n * CTOT * HW;

    for (int c = 0; c < CTOT; ++c) {
        const float* xc = xn + c * HW;
        const int wb = c * 9;
#pragma unroll
        for (int kh = 0; kh < 3; ++kh) {
            const int hh = h + kh - 1;
            if (hh < 0 || hh >= 56) continue;
            const float* rowp = xc + hh * 56;
#pragma unroll
            for (int kw = 0; kw < 3; ++kw) {
                const int ww = w + kw - 1;
                const float v = (ww >= 0 && ww < 56) ? rowp[ww] : 0.0f;
                const int wi = wb + kh * 3 + kw;
                a0 = fmaf(v, aw[wi], a0);
                a1 = fmaf(v, aw[576 + wi], a1);
                a2 = fmaf(v, aw[1152 + wi], a2);
                a3 = fmaf(v, aw[1728 + wi], a3);
            }
        }
    }
    const int sp = h * 56 + w;
    float* ao = attn + (size_t)n * 4 * HW + sp;
    // sigmoid(relu(z)) : z<=0 -> 0.5
    ao[0 * HW] = a0 > 0.f ? 1.f / (1.f + __expf(-a0)) : 0.5f;
    ao[1 * HW] = a1 > 0.f ? 1.f / (1.f + __expf(-a1)) : 0.5f;
    ao[2 * HW] = a2 > 0.f ? 1.f / (1.f + __expf(-a2)) : 0.5f;
    ao[3 * HW] = a3 > 0.f ? 1.f / (1.f + __expf(-a3)) : 0.5f;
}

// ---------- K2: per-channel sum / sumsq of x2 = x*attn ----------
// grid 8192 (= n*64+c), block 256
__global__ __launch_bounds__(256) void k_stats(const float* __restrict__ x,
                                               const float* __restrict__ attn,
                                               float* __restrict__ stats) {
    const int nc = blockIdx.x;
    const int c = nc & 63;
    const int n = nc >> 6;
    const float* xp = x + (size_t)nc * HW;
    const float* ap = attn + (size_t)(n * 4 + (c >> 4)) * HW;

    float s = 0.f, sq = 0.f;
    for (int i = threadIdx.x; i < HW; i += 256) {
        const float v = xp[i] * ap[i];
        s += v;
        sq += v * v;
    }
#pragma unroll
    for (int off = 32; off; off >>= 1) {
        s += __shfl_down(s, off);
        sq += __shfl_down(sq, off);
    }
    __shared__ float ls[4], lq[4];
    const int wid = threadIdx.x >> 6, lane = threadIdx.x & 63;
    if (lane == 0) { ls[wid] = s; lq[wid] = sq; }
    __syncthreads();
    if (threadIdx.x == 0) {
        float S = ls[0] + ls[1] + ls[2] + ls[3];
        float Q = lq[0] + lq[1] + lq[2] + lq[3];
        atomicAdd(&stats[c], S);
        atomicAdd(&stats[64 + c], Q);
    }
}

// ---------- K3: finalize scale/shift ----------
__global__ void k_finalize(const float* __restrict__ stats,
                           const float* __restrict__ gamma,
                           const float* __restrict__ beta,
                           float* __restrict__ ss) {
    const int c = threadIdx.x;  // 64 threads
    const float cnt = 401408.0f;  // 128*3136
    const float mean = stats[c] / cnt;
    const float var = stats[64 + c] / cnt - mean * mean;
    const float scale = gamma[c] * rsqrtf(var + 1e-5f);
    ss[c] = scale;
    ss[64 + c] = beta[c] - mean * scale;
}

// ---------- K4: xbnr = relu(x*attn*scale + shift) -> bf16 ----------
// grid 25088, block 256 : one float4 per thread
__global__ __launch_bounds__(256) void k_xbnr(const float* __restrict__ x,
                                              const float* __restrict__ attn,
                                              const float* __restrict__ ss,
                                              unsigned short* __restrict__ xbnr) {
    const int i4 = blockIdx.x * 256 + threadIdx.x;
    const int base = i4 * 4;
    const int plane = base / HW;            // n*64 + c
    const int i = base - plane * HW;
    const int c = plane & 63;
    const int n = plane >> 6;
    const float4 xv = *(const float4*)(x + (size_t)base);
    const float4 av = *(const float4*)(attn + (size_t)(n * 4 + (c >> 4)) * HW + i);
    const float sc = ss[c], sh = ss[64 + c];
    ushort4 o;
    o.x = f2bf(fmaxf(fmaf(xv.x * av.x, sc, sh), 0.f));
    o.y = f2bf(fmaxf(fmaf(xv.y * av.y, sc, sh), 0.f));
    o.z = f2bf(fmaxf(fmaf(xv.z * av.z, sc, sh), 0.f));
    o.w = f2bf(fmaxf(fmaf(xv.w * av.w, sc, sh), 0.f));
    *(ushort4*)(xbnr + (size_t)base) = o;
}

// ---------- K5: grouped conv3d + tanh -> gate ----------
// grid (4, 256): blockIdx.y = b*16 + oc*8 + t ; thread -> 4 outputs along w
__global__ __launch_bounds__(256) void k_conv3d(const unsigned short* __restrict__ xbnr,
                                                const float* __restrict__ w3,
                                                const float* __restrict__ b3,
                                                float* __restrict__ gate) {
    const int s = blockIdx.x * 256 + threadIdx.x;  // 0..1023, active < 784
    const int byv = blockIdx.y;
    const int t = byv & 7;
    const int oc = (byv >> 3) & 1;
    const int b = byv >> 4;
    if (s >= 784) return;
    const int q = s % 14;
    const int h = s / 14;
    const int w0 = q * 4;

    float acc0, acc1, acc2, acc3;
    acc0 = acc1 = acc2 = acc3 = b3[oc];
    const float* wg = w3 + oc * 32 * 27;  // (ic, dt, dh, dw)

    for (int ic = 0; ic < 32; ++ic) {
        const int c = oc * 32 + ic;
#pragma unroll
        for (int dt = 0; dt < 3; ++dt) {
            const int tt = t + dt - 1;
            if (tt < 0 || tt >= 8) continue;
            const unsigned short* pl = xbnr + (size_t)((b * 8 + tt) * 64 + c) * HW;
#pragma unroll
            for (int dh = 0; dh < 3; ++dh) {
                const int hh = h + dh - 1;
                if (hh < 0 || hh >= 56) continue;
                const unsigned short* row = pl + hh * 56 + w0;
                const ushort4 mid = *(const ushort4*)row;
                const float f0 = (q > 0) ? bf2f(row[-1]) : 0.f;
                const float f1 = bf2f(mid.x), f2 = bf2f(mid.y);
                const float f3 = bf2f(mid.z), f4 = bf2f(mid.w);
                const float f5 = (q < 13) ? bf2f(row[4]) : 0.f;
                const float* wp = wg + ic * 27 + dt * 9 + dh * 3;
                const float wa = wp[0], wb = wp[1], wc = wp[2];
                acc0 = fmaf(f0, wa, fmaf(f1, wb, fmaf(f2, wc, acc0)));
                acc1 = fmaf(f1, wa, fmaf(f2, wb, fmaf(f3, wc, acc1)));
                acc2 = fmaf(f2, wa, fmaf(f3, wb, fmaf(f4, wc, acc2)));
                acc3 = fmaf(f3, wa, fmaf(f4, wb, fmaf(f5, wc, acc3)));
            }
        }
    }
    float4 o;
    o.x = tanhf(acc0);
    o.y = tanhf(acc1);
    o.z = tanhf(acc2);
    o.w = tanhf(acc3);
    *(float4*)(gate + (size_t)((b * 2 + oc) * 8 + t) * HW + h * 56 + w0) = o;
}

// ---------- K6: final gating + temporal shift + interleave ----------
// grid 3136, block 256; thread = (b, c_out, h, 4w) x all 8 t
__global__ __launch_bounds__(256) void k_final(const float* __restrict__ x,
                                               const float* __restrict__ attn,
                                               const float* __restrict__ gate,
                                               float* __restrict__ out) {
    const int gt = blockIdx.x * 256 + threadIdx.x;  // 802816 exact
    const int q = gt % 14;
    int r = gt / 14;
    const int h = r % 56;
    r /= 56;
    const int co = r & 63;
    const int b = r >> 6;
    const int sp = h * 56 + q * 4;

    int cs, grp;
    if (co < 32) {
        cs = ((co & 1) << 4) | (co >> 1);
        grp = 0;
    } else {
        const int cc = co - 32;
        cs = 32 + (((cc & 1) << 4) | (cc >> 1));
        grp = 1;
    }
    const int head = cs >> 4;

    float4 x2[8], g[8];
#pragma unroll
    for (int t = 0; t < 8; ++t) {
        const int n = b * 8 + t;
        const float4 xv = *(const float4*)(x + (size_t)(n * 64 + cs) * HW + sp);
        const float4 av = *(const float4*)(attn + (size_t)(n * 4 + head) * HW + sp);
        const float4 gv = *(const float4*)(gate + (size_t)((b * 2 + grp) * 8 + t) * HW + sp);
        x2[t].x = xv.x * av.x;
        x2[t].y = xv.y * av.y;
        x2[t].z = xv.z * av.z;
        x2[t].w = xv.w * av.w;
        g[t] = gv;
    }
#pragma unroll
    for (int t = 0; t < 8; ++t) {
        float4 o;
        o.x = x2[t].x * (1.f - g[t].x);
        o.y = x2[t].y * (1.f - g[t].y);
        o.z = x2[t].z * (1.f - g[t].z);
        o.w = x2[t].w * (1.f - g[t].w);
        if (grp == 0) {
            if (t < 7) {
                o.x += x2[t + 1].x * g[t + 1].x;
                o.y += x2[t + 1].y * g[t + 1].y;
                o.z += x2[t + 1].z * g[t + 1].z;
                o.w += x2[t + 1].w * g[t + 1].w;
            }
        } else {
            if (t > 0) {
                o.x += x2[t - 1].x * g[t - 1].x;
                o.y += x2[t - 1].y * g[t - 1].y;
                o.z += x2[t - 1].z * g[t - 1].z;
                o.w += x2[t - 1].w * g[t - 1].w;
            }
        }
        *(float4*)(out + (size_t)((b * 8 + t) * 64 + co) * HW + sp) = o;
    }
}

// ---------- launch ----------
extern "C" void kernel_launch(void* const* d_in, const int* in_sizes, int n_in,
                              void* d_out, int out_size, void* d_ws, size_t ws_size,
                              hipStream_t stream) {
    const float* x = (const float*)d_in[0];
    const float* aw = (const float*)d_in[1];
    const float* ab = (const float*)d_in[2];
    const float* gamma = (const float*)d_in[3];
    const float* beta = (const float*)d_in[4];
    const float* w3 = (const float*)d_in[5];
    const float* b3 = (const float*)d_in[6];
    float* out = (float*)d_out;

    char* ws = (char*)d_ws;
    // layout: xbnr bf16 [0, 51380224) | attn f32 | gate f32 | stats | scale/shift
    unsigned short* xbnr = (unsigned short*)ws;
    float* attn = (float*)(ws + 51380224);            // 128*4*3136 f32 = 6422528 B
    float* gate = (float*)(ws + 57802752);            // 16*2*8*3136 f32 = 3211264 B
    float* stats = (float*)(ws + 61014016);           // 128 f32
    float* ss = (float*)(ws + 61014528);              // 128 f32

    hipMemsetAsync(stats, 0, 512, stream);
    k_attn<<<dim3(14, 128), dim3(64, 4), 0, stream>>>(x, aw, ab, attn);
    k_stats<<<8192, 256, 0, stream>>>(x, attn, stats);
    k_finalize<<<1, 64, 0, stream>>>(stats, gamma, beta, ss);
    k_xbnr<<<25088, 256, 0, stream>>>(x, attn, ss, xbnr);
    k_conv3d<<<dim3(4, 256), 256, 0, stream>>>(xbnr, w3, b3, gate);
    k_final<<<3136, 256, 0, stream>>>(x, attn, gate, out);
}

// Round 2
// 543.182 us; speedup vs baseline: 1.0466x; 1.0466x over previous
//
#include <hip/hip_runtime.h>
#include <hip/hip_bf16.h>

#define HW 3136      // 56*56
#define CTOT 64
#define NTOT 128
#define BB 16
#define TTT 8

// ---------- helpers ----------
static __device__ __forceinline__ float bf2f(unsigned short u) {
    union { unsigned int ui; float f; } v;
    v.ui = ((unsigned int)u) << 16;
    return v.f;
}
static __device__ __forceinline__ unsigned short f2bf(float f) {
    union { float f; unsigned int u; } v;
    v.f = f;
    unsigned int u = v.u;
    unsigned int r = (u + 0x7fffu + ((u >> 16) & 1u)) >> 16;  // round-nearest-even
    return (unsigned short)r;
}

// ---------- K1: attn = sigmoid(relu(conv2d(x, attn_w) + attn_b)) ----------
// 100352 threads: one thread = (n, h, 4-wide w quad), all 4 heads.
__global__ __launch_bounds__(256) void k_attn(const float* __restrict__ x,
                                              const float* __restrict__ aw,
                                              const float* __restrict__ ab,
                                              float* __restrict__ attn) {
    const int id = blockIdx.x * 256 + threadIdx.x;  // 100352 exact
    const int q = id % 14;
    int r = id / 14;
    const int h = r % 56;
    const int n = r / 56;
    const int w0 = q * 4;

    float acc[4][4];
#pragma unroll
    for (int hd = 0; hd < 4; ++hd) {
        const float bv = ab[hd];
#pragma unroll
        for (int j = 0; j < 4; ++j) acc[hd][j] = bv;
    }

    const float* xn = x + (size_t)n * CTOT * HW;
    for (int c = 0; c < CTOT; ++c) {
        const float* xc = xn + c * HW;
#pragma unroll
        for (int dh = 0; dh < 3; ++dh) {
            const int hh = h + dh - 1;
            if (hh < 0 || hh >= 56) continue;
            const float* row = xc + hh * 56 + w0;
            const float4 mid = *(const float4*)row;
            const float f0 = (q > 0) ? row[-1] : 0.f;
            const float f5 = (q < 13) ? row[4] : 0.f;
            const float f1 = mid.x, f2 = mid.y, f3 = mid.z, f4 = mid.w;
#pragma unroll
            for (int hd = 0; hd < 4; ++hd) {
                const float* wp = aw + hd * 576 + c * 9 + dh * 3;
                const float wa = wp[0], wb = wp[1], wc = wp[2];
                acc[hd][0] = fmaf(f0, wa, fmaf(f1, wb, fmaf(f2, wc, acc[hd][0])));
                acc[hd][1] = fmaf(f1, wa, fmaf(f2, wb, fmaf(f3, wc, acc[hd][1])));
                acc[hd][2] = fmaf(f2, wa, fmaf(f3, wb, fmaf(f4, wc, acc[hd][2])));
                acc[hd][3] = fmaf(f3, wa, fmaf(f4, wb, fmaf(f5, wc, acc[hd][3])));
            }
        }
    }
    const int sp = h * 56 + w0;
    float* ao = attn + (size_t)n * 4 * HW + sp;
#pragma unroll
    for (int hd = 0; hd < 4; ++hd) {
#pragma unroll
        for (int j = 0; j < 4; ++j) {
            const float z = acc[hd][j];
            ao[hd * HW + j] = z > 0.f ? 1.f / (1.f + __expf(-z)) : 0.5f;
        }
    }
}

// ---------- K2: per-channel sum / sumsq of x2 = x*attn ----------
// grid 8192 (= n*64+c), block 256
__global__ __launch_bounds__(256) void k_stats(const float* __restrict__ x,
                                               const float* __restrict__ attn,
                                               float* __restrict__ stats) {
    const int nc = blockIdx.x;
    const int c = nc & 63;
    const int n = nc >> 6;
    const float* xp = x + (size_t)nc * HW;
    const float* ap = attn + (size_t)(n * 4 + (c >> 4)) * HW;

    float s = 0.f, sq = 0.f;
    for (int i = threadIdx.x; i < HW; i += 256) {
        const float v = xp[i] * ap[i];
        s += v;
        sq += v * v;
    }
#pragma unroll
    for (int off = 32; off; off >>= 1) {
        s += __shfl_down(s, off);
        sq += __shfl_down(sq, off);
    }
    __shared__ float ls[4], lq[4];
    const int wid = threadIdx.x >> 6, lane = threadIdx.x & 63;
    if (lane == 0) { ls[wid] = s; lq[wid] = sq; }
    __syncthreads();
    if (threadIdx.x == 0) {
        float S = ls[0] + ls[1] + ls[2] + ls[3];
        float Q = lq[0] + lq[1] + lq[2] + lq[3];
        atomicAdd(&stats[c], S);
        atomicAdd(&stats[64 + c], Q);
    }
}

// ---------- K3: finalize scale/shift ----------
__global__ void k_finalize(const float* __restrict__ stats,
                           const float* __restrict__ gamma,
                           const float* __restrict__ beta,
                           float* __restrict__ ss) {
    const int c = threadIdx.x;  // 64 threads
    const float cnt = 401408.0f;  // 128*3136
    const float mean = stats[c] / cnt;
    const float var = stats[64 + c] / cnt - mean * mean;
    const float scale = gamma[c] * rsqrtf(var + 1e-5f);
    ss[c] = scale;
    ss[64 + c] = beta[c] - mean * scale;
}

// ---------- K4: xbnr = relu(x*attn*scale + shift) -> bf16 ----------
// grid 25088, block 256 : one float4 per thread
__global__ __launch_bounds__(256) void k_xbnr(const float* __restrict__ x,
                                              const float* __restrict__ attn,
                                              const float* __restrict__ ss,
                                              unsigned short* __restrict__ xbnr) {
    const int i4 = blockIdx.x * 256 + threadIdx.x;
    const int base = i4 * 4;
    const int plane = base / HW;            // n*64 + c
    const int i = base - plane * HW;
    const int c = plane & 63;
    const int n = plane >> 6;
    const float4 xv = *(const float4*)(x + (size_t)base);
    const float4 av = *(const float4*)(attn + (size_t)(n * 4 + (c >> 4)) * HW + i);
    const float sc = ss[c], sh = ss[64 + c];
    ushort4 o;
    o.x = f2bf(fmaxf(fmaf(xv.x * av.x, sc, sh), 0.f));
    o.y = f2bf(fmaxf(fmaf(xv.y * av.y, sc, sh), 0.f));
    o.z = f2bf(fmaxf(fmaf(xv.z * av.z, sc, sh), 0.f));
    o.w = f2bf(fmaxf(fmaf(xv.w * av.w, sc, sh), 0.f));
    *(ushort4*)(xbnr + (size_t)base) = o;
}

// ---------- K5: grouped conv3d partial sums -> atomicAdd into gate ----------
// 200704 threads: thread = (b, oc, ic-chunk of 4, h, 4-wide w quad), ALL 8 t.
// Each loaded row is reused across up to 3 temporal taps and 8 t accumulators.
__global__ __launch_bounds__(256) void k_conv3d(const unsigned short* __restrict__ xbnr,
                                                const float* __restrict__ w3,
                                                float* __restrict__ gate) {
    const int id = blockIdx.x * 256 + threadIdx.x;  // 200704 exact
    const int q = id % 14;
    int r = id / 14;
    const int h = r % 56;
    r /= 56;
    const int chunk = r & 7;
    r >>= 3;
    const int oc = r & 1;
    const int b = r >> 1;
    const int w0 = q * 4;

    float acc[8][4];
#pragma unroll
    for (int t = 0; t < 8; ++t)
#pragma unroll
        for (int j = 0; j < 4; ++j) acc[t][j] = 0.f;

    const int icg0 = chunk * 4;  // in-group input-channel base
    for (int ic = icg0; ic < icg0 + 4; ++ic) {
        const int c = oc * 32 + ic;
        const unsigned short* cbase = xbnr + (size_t)(b * 8 * 64 + c) * HW;
        const float* wic = w3 + (oc * 32 + ic) * 27;  // (dt, dh, dw)
#pragma unroll
        for (int tt = 0; tt < 8; ++tt) {
            const unsigned short* plane = cbase + (size_t)tt * (64 * HW);
#pragma unroll
            for (int dh = 0; dh < 3; ++dh) {
                const int hh = h + dh - 1;
                if (hh < 0 || hh >= 56) continue;
                const unsigned short* row = plane + hh * 56 + w0;
                const ushort4 mid = *(const ushort4*)row;
                const float f0 = (q > 0) ? bf2f(row[-1]) : 0.f;
                const float f1 = bf2f(mid.x), f2 = bf2f(mid.y);
                const float f3 = bf2f(mid.z), f4 = bf2f(mid.w);
                const float f5 = (q < 13) ? bf2f(row[4]) : 0.f;
#pragma unroll
                for (int dt = 0; dt < 3; ++dt) {
                    const int t = tt + 1 - dt;   // out[t] += in[t+dt-1]*w[dt]
                    if (t < 0 || t > 7) continue;
                    const float* wp = wic + dt * 9 + dh * 3;
                    const float wa = wp[0], wb = wp[1], wc = wp[2];
                    acc[t][0] = fmaf(f0, wa, fmaf(f1, wb, fmaf(f2, wc, acc[t][0])));
                    acc[t][1] = fmaf(f1, wa, fmaf(f2, wb, fmaf(f3, wc, acc[t][1])));
                    acc[t][2] = fmaf(f2, wa, fmaf(f3, wb, fmaf(f4, wc, acc[t][2])));
                    acc[t][3] = fmaf(f3, wa, fmaf(f4, wb, fmaf(f5, wc, acc[t][3])));
                }
            }
        }
    }
    float* gp = gate + (size_t)((b * 2 + oc) * 8) * HW + h * 56 + w0;
#pragma unroll
    for (int t = 0; t < 8; ++t) {
#pragma unroll
        for (int j = 0; j < 4; ++j)
            atomicAdd(&gp[t * HW + j], acc[t][j]);
    }
}

// ---------- K5b: gate = tanh(gate + bias) ----------
__global__ __launch_bounds__(256) void k_tanhgate(float* __restrict__ gate,
                                                  const float* __restrict__ b3) {
    const int i4 = blockIdx.x * 256 + threadIdx.x;  // 200704 exact
    const int base = i4 * 4;
    const int oc = (base / (8 * HW)) & 1;
    const float bb = b3[oc];
    float4 v = *(float4*)(gate + (size_t)base);
    v.x = tanhf(v.x + bb);
    v.y = tanhf(v.y + bb);
    v.z = tanhf(v.z + bb);
    v.w = tanhf(v.w + bb);
    *(float4*)(gate + (size_t)base) = v;
}

// ---------- K6: final gating + temporal shift + interleave ----------
// grid 3136, block 256; thread = (b, c_out, h, 4w) x all 8 t
__global__ __launch_bounds__(256) void k_final(const float* __restrict__ x,
                                               const float* __restrict__ attn,
                                               const float* __restrict__ gate,
                                               float* __restrict__ out) {
    const int gt = blockIdx.x * 256 + threadIdx.x;  // 802816 exact
    const int q = gt % 14;
    int r = gt / 14;
    const int h = r % 56;
    r /= 56;
    const int co = r & 63;
    const int b = r >> 6;
    const int sp = h * 56 + q * 4;

    int cs, grp;
    if (co < 32) {
        cs = ((co & 1) << 4) | (co >> 1);
        grp = 0;
    } else {
        const int cc = co - 32;
        cs = 32 + (((cc & 1) << 4) | (cc >> 1));
        grp = 1;
    }
    const int head = cs >> 4;

    float4 x2[8], g[8];
#pragma unroll
    for (int t = 0; t < 8; ++t) {
        const int n = b * 8 + t;
        const float4 xv = *(const float4*)(x + (size_t)(n * 64 + cs) * HW + sp);
        const float4 av = *(const float4*)(attn + (size_t)(n * 4 + head) * HW + sp);
        const float4 gv = *(const float4*)(gate + (size_t)((b * 2 + grp) * 8 + t) * HW + sp);
        x2[t].x = xv.x * av.x;
        x2[t].y = xv.y * av.y;
        x2[t].z = xv.z * av.z;
        x2[t].w = xv.w * av.w;
        g[t] = gv;
    }
#pragma unroll
    for (int t = 0; t < 8; ++t) {
        float4 o;
        o.x = x2[t].x * (1.f - g[t].x);
        o.y = x2[t].y * (1.f - g[t].y);
        o.z = x2[t].z * (1.f - g[t].z);
        o.w = x2[t].w * (1.f - g[t].w);
        if (grp == 0) {
            if (t < 7) {
                o.x += x2[t + 1].x * g[t + 1].x;
                o.y += x2[t + 1].y * g[t + 1].y;
                o.z += x2[t + 1].z * g[t + 1].z;
                o.w += x2[t + 1].w * g[t + 1].w;
            }
        } else {
            if (t > 0) {
                o.x += x2[t - 1].x * g[t - 1].x;
                o.y += x2[t - 1].y * g[t - 1].y;
                o.z += x2[t - 1].z * g[t - 1].z;
                o.w += x2[t - 1].w * g[t - 1].w;
            }
        }
        *(float4*)(out + (size_t)((b * 8 + t) * 64 + co) * HW + sp) = o;
    }
}

// ---------- launch ----------
extern "C" void kernel_launch(void* const* d_in, const int* in_sizes, int n_in,
                              void* d_out, int out_size, void* d_ws, size_t ws_size,
                              hipStream_t stream) {
    const float* x = (const float*)d_in[0];
    const float* aw = (const float*)d_in[1];
    const float* ab = (const float*)d_in[2];
    const float* gamma = (const float*)d_in[3];
    const float* beta = (const float*)d_in[4];
    const float* w3 = (const float*)d_in[5];
    const float* b3 = (const float*)d_in[6];
    float* out = (float*)d_out;

    char* ws = (char*)d_ws;
    // layout: xbnr bf16 [0, 51380224) | attn f32 | gate f32 | stats | scale/shift
    unsigned short* xbnr = (unsigned short*)ws;
    float* attn = (float*)(ws + 51380224);            // 128*4*3136 f32 = 6422528 B
    float* gate = (float*)(ws + 57802752);            // 16*2*8*3136 f32 = 3211264 B
    float* stats = (float*)(ws + 61014016);           // 128 f32
    float* ss = (float*)(ws + 61014528);              // 128 f32

    hipMemsetAsync(stats, 0, 512, stream);
    hipMemsetAsync(gate, 0, 3211264, stream);
    k_attn<<<392, 256, 0, stream>>>(x, aw, ab, attn);
    k_stats<<<8192, 256, 0, stream>>>(x, attn, stats);
    k_finalize<<<1, 64, 0, stream>>>(stats, gamma, beta, ss);
    k_xbnr<<<25088, 256, 0, stream>>>(x, attn, ss, xbnr);
    k_conv3d<<<784, 256, 0, stream>>>(xbnr, w3, gate);
    k_tanhgate<<<784, 256, 0, stream>>>(gate, b3);
    k_final<<<3136, 256, 0, stream>>>(x, attn, gate, out);
}

// Round 3
// 475.953 us; speedup vs baseline: 1.1945x; 1.1413x over previous
//
#include <hip/hip_runtime.h>
#include <hip/hip_bf16.h>

#define HW 3136      // 56*56
#define CTOT 64
#define NTOT 128
#define BB 16
#define TTT 8

// ---------- helpers ----------
static __device__ __forceinline__ float bf2f(unsigned short u) {
    union { unsigned int ui; float f; } v;
    v.ui = ((unsigned int)u) << 16;
    return v.f;
}
static __device__ __forceinline__ unsigned short f2bf(float f) {
    union { float f; unsigned int u; } v;
    v.f = f;
    unsigned int u = v.u;
    unsigned int r = (u + 0x7fffu + ((u >> 16) & 1u)) >> 16;  // round-nearest-even
    return (unsigned short)r;
}

// ---------- K1: attn = sigmoid(relu(conv2d(x, attn_w) + attn_b)) ----------
// 100352 threads: one thread = (n, h, 4-wide w quad), all 4 heads.
__global__ __launch_bounds__(256) void k_attn(const float* __restrict__ x,
                                              const float* __restrict__ aw,
                                              const float* __restrict__ ab,
                                              float* __restrict__ attn) {
    const int id = blockIdx.x * 256 + threadIdx.x;  // 100352 exact
    const int q = id % 14;
    int r = id / 14;
    const int h = r % 56;
    const int n = r / 56;
    const int w0 = q * 4;

    float acc[4][4];
#pragma unroll
    for (int hd = 0; hd < 4; ++hd) {
        const float bv = ab[hd];
#pragma unroll
        for (int j = 0; j < 4; ++j) acc[hd][j] = bv;
    }

    const float* xn = x + (size_t)n * CTOT * HW;
    for (int c = 0; c < CTOT; ++c) {
        const float* xc = xn + c * HW;
#pragma unroll
        for (int dh = 0; dh < 3; ++dh) {
            const int hh = h + dh - 1;
            if (hh < 0 || hh >= 56) continue;
            const float* row = xc + hh * 56 + w0;
            const float4 mid = *(const float4*)row;
            const float f0 = (q > 0) ? row[-1] : 0.f;
            const float f5 = (q < 13) ? row[4] : 0.f;
            const float f1 = mid.x, f2 = mid.y, f3 = mid.z, f4 = mid.w;
#pragma unroll
            for (int hd = 0; hd < 4; ++hd) {
                const float* wp = aw + hd * 576 + c * 9 + dh * 3;
                const float wa = wp[0], wb = wp[1], wc = wp[2];
                acc[hd][0] = fmaf(f0, wa, fmaf(f1, wb, fmaf(f2, wc, acc[hd][0])));
                acc[hd][1] = fmaf(f1, wa, fmaf(f2, wb, fmaf(f3, wc, acc[hd][1])));
                acc[hd][2] = fmaf(f2, wa, fmaf(f3, wb, fmaf(f4, wc, acc[hd][2])));
                acc[hd][3] = fmaf(f3, wa, fmaf(f4, wb, fmaf(f5, wc, acc[hd][3])));
            }
        }
    }
    const int sp = h * 56 + w0;
    float* ao = attn + (size_t)n * 4 * HW + sp;
#pragma unroll
    for (int hd = 0; hd < 4; ++hd) {
#pragma unroll
        for (int j = 0; j < 4; ++j) {
            const float z = acc[hd][j];
            ao[hd * HW + j] = z > 0.f ? 1.f / (1.f + __expf(-z)) : 0.5f;
        }
    }
}

// ---------- K2: per-channel sum / sumsq of x2 = x*attn ----------
// grid 8192 (= n*64+c), block 256
__global__ __launch_bounds__(256) void k_stats(const float* __restrict__ x,
                                               const float* __restrict__ attn,
                                               float* __restrict__ stats) {
    const int nc = blockIdx.x;
    const int c = nc & 63;
    const int n = nc >> 6;
    const float* xp = x + (size_t)nc * HW;
    const float* ap = attn + (size_t)(n * 4 + (c >> 4)) * HW;

    float s = 0.f, sq = 0.f;
    for (int i = threadIdx.x; i < HW; i += 256) {
        const float v = xp[i] * ap[i];
        s += v;
        sq += v * v;
    }
#pragma unroll
    for (int off = 32; off; off >>= 1) {
        s += __shfl_down(s, off);
        sq += __shfl_down(sq, off);
    }
    __shared__ float ls[4], lq[4];
    const int wid = threadIdx.x >> 6, lane = threadIdx.x & 63;
    if (lane == 0) { ls[wid] = s; lq[wid] = sq; }
    __syncthreads();
    if (threadIdx.x == 0) {
        float S = ls[0] + ls[1] + ls[2] + ls[3];
        float Q = lq[0] + lq[1] + lq[2] + lq[3];
        atomicAdd(&stats[c], S);
        atomicAdd(&stats[64 + c], Q);
    }
}

// ---------- K3: finalize scale/shift ----------
__global__ void k_finalize(const float* __restrict__ stats,
                           const float* __restrict__ gamma,
                           const float* __restrict__ beta,
                           float* __restrict__ ss) {
    const int c = threadIdx.x;  // 64 threads
    const float cnt = 401408.0f;  // 128*3136
    const float mean = stats[c] / cnt;
    const float var = stats[64 + c] / cnt - mean * mean;
    const float scale = gamma[c] * rsqrtf(var + 1e-5f);
    ss[c] = scale;
    ss[64 + c] = beta[c] - mean * scale;
}

// ---------- K4: xbnr = relu(x*attn*scale + shift) -> bf16 ----------
// grid 25088, block 256 : one float4 per thread
__global__ __launch_bounds__(256) void k_xbnr(const float* __restrict__ x,
                                              const float* __restrict__ attn,
                                              const float* __restrict__ ss,
                                              unsigned short* __restrict__ xbnr) {
    const int i4 = blockIdx.x * 256 + threadIdx.x;
    const int base = i4 * 4;
    const int plane = base / HW;            // n*64 + c
    const int i = base - plane * HW;
    const int c = plane & 63;
    const int n = plane >> 6;
    const float4 xv = *(const float4*)(x + (size_t)base);
    const float4 av = *(const float4*)(attn + (size_t)(n * 4 + (c >> 4)) * HW + i);
    const float sc = ss[c], sh = ss[64 + c];
    ushort4 o;
    o.x = f2bf(fmaxf(fmaf(xv.x * av.x, sc, sh), 0.f));
    o.y = f2bf(fmaxf(fmaf(xv.y * av.y, sc, sh), 0.f));
    o.z = f2bf(fmaxf(fmaf(xv.z * av.z, sc, sh), 0.f));
    o.w = f2bf(fmaxf(fmaf(xv.w * av.w, sc, sh), 0.f));
    *(ushort4*)(xbnr + (size_t)base) = o;
}

// ---------- K5: grouped conv3d + bias + tanh -> gate (LDS chunk-reduction) ----------
// Block 128 = 8 ic-chunks x 16 quads. Grid = b(16) * oc(2) * tile(49).
// Compute: each thread accumulates 8t x 4w partials over its 4 input channels.
// Reduce: LDS sum over the 8 chunks, then bias + tanh + coalesced store.
__global__ __launch_bounds__(128) void k_conv3d(const unsigned short* __restrict__ xbnr,
                                                const float* __restrict__ w3,
                                                const float* __restrict__ b3,
                                                float* __restrict__ gate) {
    const int tile = blockIdx.x % 49;
    const int oc = (blockIdx.x / 49) & 1;
    const int b = blockIdx.x / 98;
    const int chunk = threadIdx.x >> 4;    // 0..7
    const int qi = threadIdx.x & 15;       // 0..15
    const int quad = tile * 16 + qi;       // 0..783
    const int q = quad % 14;
    const int h = quad / 14;
    const int w0 = q * 4;

    float acc[8][4];
#pragma unroll
    for (int t = 0; t < 8; ++t)
#pragma unroll
        for (int j = 0; j < 4; ++j) acc[t][j] = 0.f;

    const int ic0 = chunk * 4;
    for (int ic = ic0; ic < ic0 + 4; ++ic) {
        const int c = oc * 32 + ic;
        const unsigned short* cbase = xbnr + (size_t)(b * 8 * 64 + c) * HW;
        const float* wic = w3 + (oc * 32 + ic) * 27;  // (dt, dh, dw)
#pragma unroll
        for (int tt = 0; tt < 8; ++tt) {
            const unsigned short* plane = cbase + (size_t)tt * (64 * HW);
#pragma unroll
            for (int dh = 0; dh < 3; ++dh) {
                const int hh = h + dh - 1;
                if (hh < 0 || hh >= 56) continue;
                const unsigned short* row = plane + hh * 56 + w0;
                const ushort4 mid = *(const ushort4*)row;
                const float f0 = (q > 0) ? bf2f(row[-1]) : 0.f;
                const float f1 = bf2f(mid.x), f2 = bf2f(mid.y);
                const float f3 = bf2f(mid.z), f4 = bf2f(mid.w);
                const float f5 = (q < 13) ? bf2f(row[4]) : 0.f;
#pragma unroll
                for (int dt = 0; dt < 3; ++dt) {
                    const int t = tt + 1 - dt;   // out[t] += in[t+dt-1]*w[dt]
                    if (t < 0 || t > 7) continue;
                    const float* wp = wic + dt * 9 + dh * 3;
                    const float wa = wp[0], wb = wp[1], wc = wp[2];
                    acc[t][0] = fmaf(f0, wa, fmaf(f1, wb, fmaf(f2, wc, acc[t][0])));
                    acc[t][1] = fmaf(f1, wa, fmaf(f2, wb, fmaf(f3, wc, acc[t][1])));
                    acc[t][2] = fmaf(f2, wa, fmaf(f3, wb, fmaf(f4, wc, acc[t][2])));
                    acc[t][3] = fmaf(f3, wa, fmaf(f4, wb, fmaf(f5, wc, acc[t][3])));
                }
            }
        }
    }

    // LDS reduction over chunks. Layout: [chunk][qi][9 float4] (pad 8->9 breaks bank alias)
    __shared__ float4 l4[8 * 16 * 9];
    float4* mine = &l4[(chunk * 16 + qi) * 9];
#pragma unroll
    for (int t = 0; t < 8; ++t) {
        float4 v;
        v.x = acc[t][0]; v.y = acc[t][1]; v.z = acc[t][2]; v.w = acc[t][3];
        mine[t] = v;
    }
    __syncthreads();

    const int rt = threadIdx.x >> 4;   // t of this thread's output
    const int rq = threadIdx.x & 15;   // quad within tile
    float4 s = l4[(0 * 16 + rq) * 9 + rt];
#pragma unroll
    for (int c = 1; c < 8; ++c) {
        const float4 v = l4[(c * 16 + rq) * 9 + rt];
        s.x += v.x; s.y += v.y; s.z += v.z; s.w += v.w;
    }
    const float bb = b3[oc];
    float4 o;
    o.x = tanhf(s.x + bb);
    o.y = tanhf(s.y + bb);
    o.z = tanhf(s.z + bb);
    o.w = tanhf(s.w + bb);
    const int outquad = tile * 16 + rq;
    *(float4*)(gate + (size_t)((b * 2 + oc) * 8 + rt) * HW + outquad * 4) = o;
}

// ---------- K6: final gating + temporal shift + interleave ----------
// grid 3136, block 256; thread = (b, c_out, h, 4w) x all 8 t
__global__ __launch_bounds__(256) void k_final(const float* __restrict__ x,
                                               const float* __restrict__ attn,
                                               const float* __restrict__ gate,
                                               float* __restrict__ out) {
    const int gt = blockIdx.x * 256 + threadIdx.x;  // 802816 exact
    const int q = gt % 14;
    int r = gt / 14;
    const int h = r % 56;
    r /= 56;
    const int co = r & 63;
    const int b = r >> 6;
    const int sp = h * 56 + q * 4;

    int cs, grp;
    if (co < 32) {
        cs = ((co & 1) << 4) | (co >> 1);
        grp = 0;
    } else {
        const int cc = co - 32;
        cs = 32 + (((cc & 1) << 4) | (cc >> 1));
        grp = 1;
    }
    const int head = cs >> 4;

    float4 x2[8], g[8];
#pragma unroll
    for (int t = 0; t < 8; ++t) {
        const int n = b * 8 + t;
        const float4 xv = *(const float4*)(x + (size_t)(n * 64 + cs) * HW + sp);
        const float4 av = *(const float4*)(attn + (size_t)(n * 4 + head) * HW + sp);
        const float4 gv = *(const float4*)(gate + (size_t)((b * 2 + grp) * 8 + t) * HW + sp);
        x2[t].x = xv.x * av.x;
        x2[t].y = xv.y * av.y;
        x2[t].z = xv.z * av.z;
        x2[t].w = xv.w * av.w;
        g[t] = gv;
    }
#pragma unroll
    for (int t = 0; t < 8; ++t) {
        float4 o;
        o.x = x2[t].x * (1.f - g[t].x);
        o.y = x2[t].y * (1.f - g[t].y);
        o.z = x2[t].z * (1.f - g[t].z);
        o.w = x2[t].w * (1.f - g[t].w);
        if (grp == 0) {
            if (t < 7) {
                o.x += x2[t + 1].x * g[t + 1].x;
                o.y += x2[t + 1].y * g[t + 1].y;
                o.z += x2[t + 1].z * g[t + 1].z;
                o.w += x2[t + 1].w * g[t + 1].w;
            }
        } else {
            if (t > 0) {
                o.x += x2[t - 1].x * g[t - 1].x;
                o.y += x2[t - 1].y * g[t - 1].y;
                o.z += x2[t - 1].z * g[t - 1].z;
                o.w += x2[t - 1].w * g[t - 1].w;
            }
        }
        *(float4*)(out + (size_t)((b * 8 + t) * 64 + co) * HW + sp) = o;
    }
}

// ---------- launch ----------
extern "C" void kernel_launch(void* const* d_in, const int* in_sizes, int n_in,
                              void* d_out, int out_size, void* d_ws, size_t ws_size,
                              hipStream_t stream) {
    const float* x = (const float*)d_in[0];
    const float* aw = (const float*)d_in[1];
    const float* ab = (const float*)d_in[2];
    const float* gamma = (const float*)d_in[3];
    const float* beta = (const float*)d_in[4];
    const float* w3 = (const float*)d_in[5];
    const float* b3 = (const float*)d_in[6];
    float* out = (float*)d_out;

    char* ws = (char*)d_ws;
    // layout: xbnr bf16 [0, 51380224) | attn f32 | gate f32 | stats | scale/shift
    unsigned short* xbnr = (unsigned short*)ws;
    float* attn = (float*)(ws + 51380224);            // 128*4*3136 f32 = 6422528 B
    float* gate = (float*)(ws + 57802752);            // 16*2*8*3136 f32 = 3211264 B
    float* stats = (float*)(ws + 61014016);           // 128 f32
    float* ss = (float*)(ws + 61014528);              // 128 f32

    hipMemsetAsync(stats, 0, 512, stream);
    k_attn<<<392, 256, 0, stream>>>(x, aw, ab, attn);
    k_stats<<<8192, 256, 0, stream>>>(x, attn, stats);
    k_finalize<<<1, 64, 0, stream>>>(stats, gamma, beta, ss);
    k_xbnr<<<25088, 256, 0, stream>>>(x, attn, ss, xbnr);
    k_conv3d<<<1568, 128, 0, stream>>>(xbnr, w3, b3, gate);
    k_final<<<3136, 256, 0, stream>>>(x, attn, gate, out);
}

// Round 4
// 459.530 us; speedup vs baseline: 1.2371x; 1.0357x over previous
//
#include <hip/hip_runtime.h>
#include <hip/hip_bf16.h>

#define HW 3136      // 56*56
#define CTOT 64
#define NTOT 128
#define BB 16
#define TTT 8

// ---------- helpers ----------
static __device__ __forceinline__ float bf2f(unsigned short u) {
    union { unsigned int ui; float f; } v;
    v.ui = ((unsigned int)u) << 16;
    return v.f;
}
static __device__ __forceinline__ unsigned short f2bf(float f) {
    union { float f; unsigned int u; } v;
    v.f = f;
    unsigned int u = v.u;
    unsigned int r = (u + 0x7fffu + ((u >> 16) & 1u)) >> 16;  // round-nearest-even
    return (unsigned short)r;
}

// ---------- K0: repack attn weights to [c][dh][kw][head] ----------
__global__ void k_repack(const float* __restrict__ aw, float* __restrict__ wpk) {
    const int idx = blockIdx.x * 256 + threadIdx.x;  // 2304 exact
    if (idx >= 2304) return;
    const int hd = idx & 3;
    const int kw = (idx >> 2) % 3;
    const int dh = (idx / 12) % 3;
    const int c = idx / 36;
    wpk[idx] = aw[hd * 576 + c * 9 + dh * 3 + kw];
}

// ---------- K1: attn = sigmoid(relu(conv2d(x, attn_w) + attn_b)) ----------
// Block 128 = 8 chunks(8ch) x 16 quads; grid = n(128) * tile(49). LDS chunk-reduce.
__global__ __launch_bounds__(128) void k_attn(const float* __restrict__ x,
                                              const float* __restrict__ wpk,
                                              const float* __restrict__ ab,
                                              float* __restrict__ attn) {
    const int tile = blockIdx.x % 49;
    const int n = blockIdx.x / 49;
    const int chunk = threadIdx.x >> 4;    // 0..7
    const int qi = threadIdx.x & 15;       // 0..15
    const int quad = tile * 16 + qi;       // 0..783
    const int q = quad % 14;
    const int h = quad / 14;
    const int w0 = q * 4;

    float acc[4][4];
#pragma unroll
    for (int hd = 0; hd < 4; ++hd)
#pragma unroll
        for (int j = 0; j < 4; ++j) acc[hd][j] = 0.f;

    const float* xn = x + (size_t)n * CTOT * HW;
    const int c0 = chunk * 8;
    for (int c = c0; c < c0 + 8; ++c) {
        const float* xc = xn + c * HW;
#pragma unroll
        for (int dh = 0; dh < 3; ++dh) {
            const int hh = h + dh - 1;
            if (hh < 0 || hh >= 56) continue;
            const float* row = xc + hh * 56 + w0;
            const float4 mid = *(const float4*)row;
            const float f0 = (q > 0) ? row[-1] : 0.f;
            const float f5 = (q < 13) ? row[4] : 0.f;
            const float f1 = mid.x, f2 = mid.y, f3 = mid.z, f4 = mid.w;
            const float* wb = wpk + (c * 3 + dh) * 12;
            const float4 wk0 = *(const float4*)(wb);
            const float4 wk1 = *(const float4*)(wb + 4);
            const float4 wk2 = *(const float4*)(wb + 8);
            const float fs[6] = {f0, f1, f2, f3, f4, f5};
#pragma unroll
            for (int j = 0; j < 4; ++j) {
                acc[0][j] = fmaf(fs[j], wk0.x, fmaf(fs[j + 1], wk1.x, fmaf(fs[j + 2], wk2.x, acc[0][j])));
                acc[1][j] = fmaf(fs[j], wk0.y, fmaf(fs[j + 1], wk1.y, fmaf(fs[j + 2], wk2.y, acc[1][j])));
                acc[2][j] = fmaf(fs[j], wk0.z, fmaf(fs[j + 1], wk1.z, fmaf(fs[j + 2], wk2.z, acc[2][j])));
                acc[3][j] = fmaf(fs[j], wk0.w, fmaf(fs[j + 1], wk1.w, fmaf(fs[j + 2], wk2.w, acc[3][j])));
            }
        }
    }

    // LDS reduce over the 8 chunks. l[chunk][qi][16 floats + 1 pad]
    __shared__ float l[8][16][17];
    float* mine = &l[chunk][qi][0];
#pragma unroll
    for (int hd = 0; hd < 4; ++hd)
#pragma unroll
        for (int j = 0; j < 4; ++j) mine[hd * 4 + j] = acc[hd][j];
    __syncthreads();

    if (threadIdx.x < 64) {
        const int hd = threadIdx.x >> 4;
        const int rq = threadIdx.x & 15;
        float s0 = ab[hd], s1 = s0, s2 = s0, s3 = s0;
#pragma unroll
        for (int cch = 0; cch < 8; ++cch) {
            const float* p = &l[cch][rq][hd * 4];
            s0 += p[0]; s1 += p[1]; s2 += p[2]; s3 += p[3];
        }
        float4 o;
        o.x = s0 > 0.f ? 1.f / (1.f + __expf(-s0)) : 0.5f;
        o.y = s1 > 0.f ? 1.f / (1.f + __expf(-s1)) : 0.5f;
        o.z = s2 > 0.f ? 1.f / (1.f + __expf(-s2)) : 0.5f;
        o.w = s3 > 0.f ? 1.f / (1.f + __expf(-s3)) : 0.5f;
        *(float4*)(attn + (size_t)(n * 4 + hd) * HW + (tile * 16 + rq) * 4) = o;
    }
}

// ---------- K2: per-channel sum / sumsq of x2 = x*attn ----------
// grid 8192 (= n*64+c), block 256
__global__ __launch_bounds__(256) void k_stats(const float* __restrict__ x,
                                               const float* __restrict__ attn,
                                               float* __restrict__ stats) {
    const int nc = blockIdx.x;
    const int c = nc & 63;
    const int n = nc >> 6;
    const float* xp = x + (size_t)nc * HW;
    const float* ap = attn + (size_t)(n * 4 + (c >> 4)) * HW;

    float s = 0.f, sq = 0.f;
    for (int i = threadIdx.x; i < HW; i += 256) {
        const float v = xp[i] * ap[i];
        s += v;
        sq += v * v;
    }
#pragma unroll
    for (int off = 32; off; off >>= 1) {
        s += __shfl_down(s, off);
        sq += __shfl_down(sq, off);
    }
    __shared__ float ls[4], lq[4];
    const int wid = threadIdx.x >> 6, lane = threadIdx.x & 63;
    if (lane == 0) { ls[wid] = s; lq[wid] = sq; }
    __syncthreads();
    if (threadIdx.x == 0) {
        float S = ls[0] + ls[1] + ls[2] + ls[3];
        float Q = lq[0] + lq[1] + lq[2] + lq[3];
        atomicAdd(&stats[c], S);
        atomicAdd(&stats[64 + c], Q);
    }
}

// ---------- K3: finalize scale/shift ----------
__global__ void k_finalize(const float* __restrict__ stats,
                           const float* __restrict__ gamma,
                           const float* __restrict__ beta,
                           float* __restrict__ ss) {
    const int c = threadIdx.x;  // 64 threads
    const float cnt = 401408.0f;  // 128*3136
    const float mean = stats[c] / cnt;
    const float var = stats[64 + c] / cnt - mean * mean;
    const float scale = gamma[c] * rsqrtf(var + 1e-5f);
    ss[c] = scale;
    ss[64 + c] = beta[c] - mean * scale;
}

// ---------- K4: xbnr = relu(x*attn*scale + shift) -> bf16 ----------
// grid 25088, block 256 : one float4 per thread
__global__ __launch_bounds__(256) void k_xbnr(const float* __restrict__ x,
                                              const float* __restrict__ attn,
                                              const float* __restrict__ ss,
                                              unsigned short* __restrict__ xbnr) {
    const int i4 = blockIdx.x * 256 + threadIdx.x;
    const int base = i4 * 4;
    const int plane = base / HW;            // n*64 + c
    const int i = base - plane * HW;
    const int c = plane & 63;
    const int n = plane >> 6;
    const float4 xv = *(const float4*)(x + (size_t)base);
    const float4 av = *(const float4*)(attn + (size_t)(n * 4 + (c >> 4)) * HW + i);
    const float sc = ss[c], sh = ss[64 + c];
    ushort4 o;
    o.x = f2bf(fmaxf(fmaf(xv.x * av.x, sc, sh), 0.f));
    o.y = f2bf(fmaxf(fmaf(xv.y * av.y, sc, sh), 0.f));
    o.z = f2bf(fmaxf(fmaf(xv.z * av.z, sc, sh), 0.f));
    o.w = f2bf(fmaxf(fmaf(xv.w * av.w, sc, sh), 0.f));
    *(ushort4*)(xbnr + (size_t)base) = o;
}

// ---------- K5: grouped conv3d + bias + tanh -> gate (LDS chunk-reduction) ----------
// Block 128 = 8 ic-chunks x 16 quads. Grid = b(16) * oc(2) * tile(49).
__global__ __launch_bounds__(128) void k_conv3d(const unsigned short* __restrict__ xbnr,
                                                const float* __restrict__ w3,
                                                const float* __restrict__ b3,
                                                float* __restrict__ gate) {
    const int tile = blockIdx.x % 49;
    const int oc = (blockIdx.x / 49) & 1;
    const int b = blockIdx.x / 98;
    const int chunk = threadIdx.x >> 4;    // 0..7
    const int qi = threadIdx.x & 15;       // 0..15
    const int quad = tile * 16 + qi;       // 0..783
    const int q = quad % 14;
    const int h = quad / 14;
    const int w0 = q * 4;

    float acc[8][4];
#pragma unroll
    for (int t = 0; t < 8; ++t)
#pragma unroll
        for (int j = 0; j < 4; ++j) acc[t][j] = 0.f;

    const int ic0 = chunk * 4;
    for (int ic = ic0; ic < ic0 + 4; ++ic) {
        const int c = oc * 32 + ic;
        const unsigned short* cbase = xbnr + (size_t)(b * 8 * 64 + c) * HW;
        const float* wic = w3 + (oc * 32 + ic) * 27;  // (dt, dh, dw)
#pragma unroll
        for (int tt = 0; tt < 8; ++tt) {
            const unsigned short* plane = cbase + (size_t)tt * (64 * HW);
#pragma unroll
            for (int dh = 0; dh < 3; ++dh) {
                const int hh = h + dh - 1;
                if (hh < 0 || hh >= 56) continue;
                const unsigned short* row = plane + hh * 56 + w0;
                const ushort4 mid = *(const ushort4*)row;
                const float f0 = (q > 0) ? bf2f(row[-1]) : 0.f;
                const float f1 = bf2f(mid.x), f2 = bf2f(mid.y);
                const float f3 = bf2f(mid.z), f4 = bf2f(mid.w);
                const float f5 = (q < 13) ? bf2f(row[4]) : 0.f;
#pragma unroll
                for (int dt = 0; dt < 3; ++dt) {
                    const int t = tt + 1 - dt;   // out[t] += in[t+dt-1]*w[dt]
                    if (t < 0 || t > 7) continue;
                    const float* wp = wic + dt * 9 + dh * 3;
                    const float wa = wp[0], wb = wp[1], wc = wp[2];
                    acc[t][0] = fmaf(f0, wa, fmaf(f1, wb, fmaf(f2, wc, acc[t][0])));
                    acc[t][1] = fmaf(f1, wa, fmaf(f2, wb, fmaf(f3, wc, acc[t][1])));
                    acc[t][2] = fmaf(f2, wa, fmaf(f3, wb, fmaf(f4, wc, acc[t][2])));
                    acc[t][3] = fmaf(f3, wa, fmaf(f4, wb, fmaf(f5, wc, acc[t][3])));
                }
            }
        }
    }

    // LDS reduction over chunks. Layout: [chunk][qi][9 float4] (pad 8->9 breaks bank alias)
    __shared__ float4 l4[8 * 16 * 9];
    float4* mine = &l4[(chunk * 16 + qi) * 9];
#pragma unroll
    for (int t = 0; t < 8; ++t) {
        float4 v;
        v.x = acc[t][0]; v.y = acc[t][1]; v.z = acc[t][2]; v.w = acc[t][3];
        mine[t] = v;
    }
    __syncthreads();

    const int rt = threadIdx.x >> 4;   // t of this thread's output
    const int rq = threadIdx.x & 15;   // quad within tile
    float4 s = l4[(0 * 16 + rq) * 9 + rt];
#pragma unroll
    for (int c = 1; c < 8; ++c) {
        const float4 v = l4[(c * 16 + rq) * 9 + rt];
        s.x += v.x; s.y += v.y; s.z += v.z; s.w += v.w;
    }
    const float bb = b3[oc];
    float4 o;
    o.x = tanhf(s.x + bb);
    o.y = tanhf(s.y + bb);
    o.z = tanhf(s.z + bb);
    o.w = tanhf(s.w + bb);
    const int outquad = tile * 16 + rq;
    *(float4*)(gate + (size_t)((b * 2 + oc) * 8 + rt) * HW + outquad * 4) = o;
}

// ---------- K6: final gating + temporal shift + interleave ----------
// grid 3136, block 256; thread = (b, c_out, h, 4w) x all 8 t
__global__ __launch_bounds__(256) void k_final(const float* __restrict__ x,
                                               const float* __restrict__ attn,
                                               const float* __restrict__ gate,
                                               float* __restrict__ out) {
    const int gt = blockIdx.x * 256 + threadIdx.x;  // 802816 exact
    const int q = gt % 14;
    int r = gt / 14;
    const int h = r % 56;
    r /= 56;
    const int co = r & 63;
    const int b = r >> 6;
    const int sp = h * 56 + q * 4;

    int cs, grp;
    if (co < 32) {
        cs = ((co & 1) << 4) | (co >> 1);
        grp = 0;
    } else {
        const int cc = co - 32;
        cs = 32 + (((cc & 1) << 4) | (cc >> 1));
        grp = 1;
    }
    const int head = cs >> 4;

    float4 x2[8], g[8];
#pragma unroll
    for (int t = 0; t < 8; ++t) {
        const int n = b * 8 + t;
        const float4 xv = *(const float4*)(x + (size_t)(n * 64 + cs) * HW + sp);
        const float4 av = *(const float4*)(attn + (size_t)(n * 4 + head) * HW + sp);
        const float4 gv = *(const float4*)(gate + (size_t)((b * 2 + grp) * 8 + t) * HW + sp);
        x2[t].x = xv.x * av.x;
        x2[t].y = xv.y * av.y;
        x2[t].z = xv.z * av.z;
        x2[t].w = xv.w * av.w;
        g[t] = gv;
    }
#pragma unroll
    for (int t = 0; t < 8; ++t) {
        float4 o;
        o.x = x2[t].x * (1.f - g[t].x);
        o.y = x2[t].y * (1.f - g[t].y);
        o.z = x2[t].z * (1.f - g[t].z);
        o.w = x2[t].w * (1.f - g[t].w);
        if (grp == 0) {
            if (t < 7) {
                o.x += x2[t + 1].x * g[t + 1].x;
                o.y += x2[t + 1].y * g[t + 1].y;
                o.z += x2[t + 1].z * g[t + 1].z;
                o.w += x2[t + 1].w * g[t + 1].w;
            }
        } else {
            if (t > 0) {
                o.x += x2[t - 1].x * g[t - 1].x;
                o.y += x2[t - 1].y * g[t - 1].y;
                o.z += x2[t - 1].z * g[t - 1].z;
                o.w += x2[t - 1].w * g[t - 1].w;
            }
        }
        *(float4*)(out + (size_t)((b * 8 + t) * 64 + co) * HW + sp) = o;
    }
}

// ---------- launch ----------
extern "C" void kernel_launch(void* const* d_in, const int* in_sizes, int n_in,
                              void* d_out, int out_size, void* d_ws, size_t ws_size,
                              hipStream_t stream) {
    const float* x = (const float*)d_in[0];
    const float* aw = (const float*)d_in[1];
    const float* ab = (const float*)d_in[2];
    const float* gamma = (const float*)d_in[3];
    const float* beta = (const float*)d_in[4];
    const float* w3 = (const float*)d_in[5];
    const float* b3 = (const float*)d_in[6];
    float* out = (float*)d_out;

    char* ws = (char*)d_ws;
    // layout: xbnr bf16 [0, 51380224) | attn f32 | gate f32 | stats | ss | wpk
    unsigned short* xbnr = (unsigned short*)ws;
    float* attn = (float*)(ws + 51380224);            // 128*4*3136 f32 = 6422528 B
    float* gate = (float*)(ws + 57802752);            // 16*2*8*3136 f32 = 3211264 B
    float* stats = (float*)(ws + 61014016);           // 128 f32
    float* ss = (float*)(ws + 61014528);              // 128 f32
    float* wpk = (float*)(ws + 61015040);             // 2304 f32

    hipMemsetAsync(stats, 0, 512, stream);
    k_repack<<<9, 256, 0, stream>>>(aw, wpk);
    k_attn<<<6272, 128, 0, stream>>>(x, wpk, ab, attn);
    k_stats<<<8192, 256, 0, stream>>>(x, attn, stats);
    k_finalize<<<1, 64, 0, stream>>>(stats, gamma, beta, ss);
    k_xbnr<<<25088, 256, 0, stream>>>(x, attn, ss, xbnr);
    k_conv3d<<<1568, 128, 0, stream>>>(xbnr, w3, b3, gate);
    k_final<<<3136, 256, 0, stream>>>(x, attn, gate, out);
}